// Round 2
// baseline (2707.714 us; speedup 1.0000x reference)
//
#include <hip/hip_runtime.h>
#include <math.h>

#define NROWS 16384   // b*n
#define DDIM  256
#define HDIM  128
#define NSEQ  4096

// ---- workspace layout (float offsets) ----
#define OFF_MOM   0                      // 9 used, pad 16
#define OFF_S1    16
#define OFF_T1    144
#define OFF_CSUM  272
#define OFF_CSQ   528
#define OFF_S2    784
#define OFF_T2    1040
#define OFF_H2F   2048
#define OFF_Q     (OFF_H2F + NROWS*DDIM)
#define OFF_K     (OFF_Q  + NROWS*DDIM)
#define OFF_V     (OFF_K  + NROWS*DDIM)
// h1 lives in d_out (8 MB <= 16 MB), consumed before attention writes output.

// ---------------- xyz second moments (for analytic BN1 stats) ----------------
__global__ void k_xyz_stats(const float* __restrict__ xyz, float* __restrict__ mom) {
  int i = blockIdx.x * blockDim.x + threadIdx.x;   // exactly NROWS threads
  float x = xyz[3*i+0], y = xyz[3*i+1], z = xyz[3*i+2];
  float v[9] = {x, y, z, x*x, x*y, x*z, y*y, y*z, z*z};
#pragma unroll
  for (int j = 0; j < 9; ++j) {
    float s = v[j];
#pragma unroll
    for (int off = 32; off > 0; off >>= 1) s += __shfl_down(s, off);
    if ((threadIdx.x & 63) == 0) atomicAdd(&mom[j], s);
  }
}

// mean_j = mu . W1[:,j]  (b1 cancels in BN), var_j = W1col^T Cov W1col
__global__ void k_bn1_coeff(const float* __restrict__ mom, const float* __restrict__ W1,
                            const float* __restrict__ g1, const float* __restrict__ be1,
                            float* __restrict__ s1, float* __restrict__ t1) {
  int j = threadIdx.x;  // 128
  const float invN = 1.0f / NROWS;
  float mu0 = mom[0]*invN, mu1 = mom[1]*invN, mu2 = mom[2]*invN;
  float c00 = mom[3]*invN - mu0*mu0, c01 = mom[4]*invN - mu0*mu1, c02 = mom[5]*invN - mu0*mu2;
  float c11 = mom[6]*invN - mu1*mu1, c12 = mom[7]*invN - mu1*mu2, c22 = mom[8]*invN - mu2*mu2;
  float w0 = W1[j], w1 = W1[HDIM + j], w2 = W1[2*HDIM + j];
  float meanw = mu0*w0 + mu1*w1 + mu2*w2;
  float var = c00*w0*w0 + c11*w1*w1 + c22*w2*w2
            + 2.0f*(c01*w0*w1 + c02*w0*w2 + c12*w1*w2);
  float s = g1[j] * rsqrtf(var + 1e-5f);
  s1[j] = s;
  t1[j] = be1[j] - meanw * s;
}

// h1 = relu((x@W1)*s1 + t1)   (b1 folded out exactly)
__global__ void k_pn1(const float* __restrict__ xyz, const float* __restrict__ W1,
                      const float* __restrict__ s1, const float* __restrict__ t1,
                      float* __restrict__ h1) {
  int t = blockIdx.x * blockDim.x + threadIdx.x;   // NROWS*HDIM threads
  int j = t & (HDIM-1), row = t >> 7;
  float x = xyz[3*row+0], y = xyz[3*row+1], z = xyz[3*row+2];
  float acc = x*W1[j] + y*W1[HDIM + j] + z*W1[2*HDIM + j];
  float v = fmaf(acc, s1[j], t1[j]);
  h1[t] = fmaxf(v, 0.0f);
}

// ---------------- fp32 GEMM: C[M][N] = A[M][K] @ B[K][N] (+bias) ----------------
// BM=BN=128, BK=16, 256 threads, 8x8 per thread (rows {4ty,64+4ty}, cols {4tx,64+4tx})
__global__ __launch_bounds__(256) void k_gemm(const float* __restrict__ A,
    const float* __restrict__ B, const float* __restrict__ bias,
    float* __restrict__ C, int M, int N, int K) {
  __shared__ float As[16][132];
  __shared__ float Bs[16][132];
  const int tid = threadIdx.x;
  const int tx = tid & 15, ty = tid >> 4;
  const int m0 = blockIdx.x * 128, n0 = blockIdx.y * 128;
  float acc[2][4][2][4] = {};

  for (int kb = 0; kb < K; kb += 16) {
    __syncthreads();
#pragma unroll
    for (int u = 0; u < 2; ++u) {
      int idx4 = tid + u * 256;                  // 0..511
      int am = idx4 >> 2, ak = (idx4 & 3) << 2;  // A: 128 rows x 16 k
      float4 av = *(const float4*)&A[(size_t)(m0 + am) * K + kb + ak];
      As[ak+0][am] = av.x; As[ak+1][am] = av.y; As[ak+2][am] = av.z; As[ak+3][am] = av.w;
      int bk = idx4 >> 5, bc = (idx4 & 31) << 2; // B: 16 k x 128 cols
      float4 bv = *(const float4*)&B[(size_t)(kb + bk) * N + n0 + bc];
      *(float4*)&Bs[bk][bc] = bv;
    }
    __syncthreads();
#pragma unroll
    for (int kk = 0; kk < 16; ++kk) {
      float4 a0 = *(const float4*)&As[kk][4*ty];
      float4 a1 = *(const float4*)&As[kk][64 + 4*ty];
      float4 b0 = *(const float4*)&Bs[kk][4*tx];
      float4 b1 = *(const float4*)&Bs[kk][64 + 4*tx];
      float av[2][4] = {{a0.x,a0.y,a0.z,a0.w},{a1.x,a1.y,a1.z,a1.w}};
      float bv[2][4] = {{b0.x,b0.y,b0.z,b0.w},{b1.x,b1.y,b1.z,b1.w}};
#pragma unroll
      for (int ri = 0; ri < 2; ++ri)
#pragma unroll
        for (int i = 0; i < 4; ++i)
#pragma unroll
          for (int rj = 0; rj < 2; ++rj)
#pragma unroll
            for (int j = 0; j < 4; ++j)
              acc[ri][i][rj][j] = fmaf(av[ri][i], bv[rj][j], acc[ri][i][rj][j]);
    }
  }
#pragma unroll
  for (int ri = 0; ri < 2; ++ri)
#pragma unroll
    for (int i = 0; i < 4; ++i) {
      int r = m0 + ri*64 + 4*ty + i;
#pragma unroll
      for (int rj = 0; rj < 2; ++rj) {
        int c = n0 + rj*64 + 4*tx;
        float4 o;
        o.x = acc[ri][i][rj][0]; o.y = acc[ri][i][rj][1];
        o.z = acc[ri][i][rj][2]; o.w = acc[ri][i][rj][3];
        if (bias) { o.x += bias[c]; o.y += bias[c+1]; o.z += bias[c+2]; o.w += bias[c+3]; }
        *(float4*)&C[(size_t)r * N + c] = o;
      }
    }
}

// per-column sum / sumsq of h2pre (for BN2)
__global__ void k_colstats(const float* __restrict__ h2, float* __restrict__ cs,
                           float* __restrict__ cq) {
  int j = threadIdx.x;                  // 256
  size_t r0 = (size_t)blockIdx.x * 64;  // 256 blocks
  float s = 0.f, q = 0.f;
  for (int r = 0; r < 64; ++r) {
    float v = h2[(r0 + r) * DDIM + j];
    s += v; q += v * v;
  }
  atomicAdd(&cs[j], s);
  atomicAdd(&cq[j], q);
}

__global__ void k_bn2_coeff(const float* __restrict__ cs, const float* __restrict__ cq,
                            const float* __restrict__ g2, const float* __restrict__ be2,
                            float* __restrict__ s2, float* __restrict__ t2) {
  int j = threadIdx.x;  // 256
  const float invN = 1.0f / NROWS;
  float mean = cs[j] * invN;
  float var = cq[j] * invN - mean * mean;
  float s = g2[j] * rsqrtf(var + 1e-5f);
  s2[j] = s;
  t2[j] = be2[j] - mean * s;
}

// f = relu(h2*s2 + t2) + features   (in place over h2 buffer)
__global__ void k_makef(float* __restrict__ h2f, const float* __restrict__ feats,
                        const float* __restrict__ s2, const float* __restrict__ t2) {
  size_t i4 = (size_t)blockIdx.x * blockDim.x + threadIdx.x;  // NROWS*DDIM/4
  int c = ((int)i4 & 63) << 2;
  float4 h = *(float4*)&h2f[i4*4];
  float4 f = *(const float4*)&feats[i4*4];
  float4 s = *(const float4*)&s2[c];
  float4 t = *(const float4*)&t2[c];
  h.x = fmaxf(fmaf(h.x, s.x, t.x), 0.f) + f.x;
  h.y = fmaxf(fmaf(h.y, s.y, t.y), 0.f) + f.y;
  h.z = fmaxf(fmaf(h.z, s.z, t.z), 0.f) + f.z;
  h.w = fmaxf(fmaf(h.w, s.w, t.w), 0.f) + f.w;
  *(float4*)&h2f[i4*4] = h;
}

// ---------------- fp32 flash attention ----------------
// 512 blocks = 4 batches x 128 q-tiles(32 rows). 256 thr = 4 waves x (8 rows x 8 octants).
// Lane owns one q-row + one 32-dim octant: Q(32f) and O(32f) in registers.
// K/V tiles (32 keys) in LDS; slot index (oc<<3)|(oc^rr) is bijective, reads
// broadcast within octant groups and hit 8 distinct bank groups across octants.
__global__ __launch_bounds__(256, 2) void k_attn(const float* __restrict__ Qg,
    const float* __restrict__ Kg, const float* __restrict__ Vg,
    float* __restrict__ Og) {
  __shared__ float sK[32 * 256];
  __shared__ float sV[32 * 256];
  const int tid = threadIdx.x;
  const int l = tid & 63, w = tid >> 6;
  const int oc = l >> 3, rr = l & 7;
  const int b = blockIdx.x >> 7, qt = blockIdx.x & 127;
  const int row = qt * 32 + w * 8 + rr;
  const size_t rowg = ((size_t)b * NSEQ + row) * DDIM;
  const float* __restrict__ Kbase = Kg + (size_t)b * NSEQ * DDIM;
  const float* __restrict__ Vbase = Vg + (size_t)b * NSEQ * DDIM;

  float4 q[8];
#pragma unroll
  for (int dc = 0; dc < 8; ++dc) {
    float4 t4 = *(const float4*)&Qg[rowg + oc*32 + dc*4];
    q[dc].x = t4.x * 0.0625f; q[dc].y = t4.y * 0.0625f;   // fold 1/sqrt(256)
    q[dc].z = t4.z * 0.0625f; q[dc].w = t4.w * 0.0625f;
  }
  float4 o[8];
#pragma unroll
  for (int dc = 0; dc < 8; ++dc) o[dc] = make_float4(0.f, 0.f, 0.f, 0.f);
  float m = -1e30f, lsum = 0.f;

  const int dst = (36*oc) ^ (4*rr);   // swizzled float offset within LDS row
  const int qbase = 36 * oc;          // read base (bits 2..4 get XORed by dc)

  for (int kt = 0; kt < NSEQ/32; ++kt) {
    const int kb = kt * 32;
    __syncthreads();
#pragma unroll
    for (int it = 0; it < 8; ++it) {
      int r = w + it*4;
      *(float4*)&sK[r*256 + dst] = *(const float4*)&Kbase[(size_t)(kb+r)*DDIM + l*4];
      *(float4*)&sV[r*256 + dst] = *(const float4*)&Vbase[(size_t)(kb+r)*DDIM + l*4];
    }
    __syncthreads();

    float s[32];
#pragma unroll
    for (int k = 0; k < 32; ++k) {
      const int base = k*256 + qbase;
      float a0 = 0.f, a1 = 0.f;
#pragma unroll
      for (int dc = 0; dc < 8; dc += 2) {
        float4 k0 = *(const float4*)&sK[base ^ (dc << 2)];
        float4 k1 = *(const float4*)&sK[base ^ ((dc+1) << 2)];
        a0 = fmaf(q[dc].x,   k0.x, a0); a0 = fmaf(q[dc].y,   k0.y, a0);
        a0 = fmaf(q[dc].z,   k0.z, a0); a0 = fmaf(q[dc].w,   k0.w, a0);
        a1 = fmaf(q[dc+1].x, k1.x, a1); a1 = fmaf(q[dc+1].y, k1.y, a1);
        a1 = fmaf(q[dc+1].z, k1.z, a1); a1 = fmaf(q[dc+1].w, k1.w, a1);
      }
      float a = a0 + a1;
      a += __shfl_xor(a, 8);
      a += __shfl_xor(a, 16);
      a += __shfl_xor(a, 32);
      s[k] = a;
    }
    float tm = s[0];
#pragma unroll
    for (int k = 1; k < 32; ++k) tm = fmaxf(tm, s[k]);
    float mn = fmaxf(m, tm);
    float corr = __expf(m - mn);
    m = mn;
    float ps = 0.f;
#pragma unroll
    for (int k = 0; k < 32; ++k) { s[k] = __expf(s[k] - mn); ps += s[k]; }
    lsum = lsum * corr + ps;
#pragma unroll
    for (int dc = 0; dc < 8; ++dc) {
      o[dc].x *= corr; o[dc].y *= corr; o[dc].z *= corr; o[dc].w *= corr;
    }
#pragma unroll
    for (int k = 0; k < 32; ++k) {
      const int base = k*256 + qbase;
      const float p = s[k];
#pragma unroll
      for (int dc = 0; dc < 8; ++dc) {
        float4 vv = *(const float4*)&sV[base ^ (dc << 2)];
        o[dc].x = fmaf(p, vv.x, o[dc].x);
        o[dc].y = fmaf(p, vv.y, o[dc].y);
        o[dc].z = fmaf(p, vv.z, o[dc].z);
        o[dc].w = fmaf(p, vv.w, o[dc].w);
      }
    }
  }
  const float inv = 1.0f / lsum;
#pragma unroll
  for (int dc = 0; dc < 8; ++dc) {
    float4 r4;
    r4.x = o[dc].x*inv; r4.y = o[dc].y*inv; r4.z = o[dc].z*inv; r4.w = o[dc].w*inv;
    *(float4*)&Og[rowg + oc*32 + dc*4] = r4;
  }
}

extern "C" void kernel_launch(void* const* d_in, const int* in_sizes, int n_in,
                              void* d_out, int out_size, void* d_ws, size_t ws_size,
                              hipStream_t stream) {
  (void)in_sizes; (void)n_in; (void)out_size; (void)ws_size;
  const float* xyz   = (const float*)d_in[0];
  const float* feats = (const float*)d_in[1];
  const float* W1    = (const float*)d_in[2];
  // d_in[3] = b1: cancels exactly inside BN1 -> unused
  const float* g1    = (const float*)d_in[4];
  const float* be1   = (const float*)d_in[5];
  const float* W2    = (const float*)d_in[6];
  const float* b2    = (const float*)d_in[7];
  const float* g2    = (const float*)d_in[8];
  const float* be2   = (const float*)d_in[9];
  const float* Wq    = (const float*)d_in[10];
  const float* Wk    = (const float*)d_in[11];
  const float* Wv    = (const float*)d_in[12];

  float* ws  = (float*)d_ws;
  float* mom = ws + OFF_MOM;
  float* s1  = ws + OFF_S1;  float* t1 = ws + OFF_T1;
  float* cs  = ws + OFF_CSUM; float* cq = ws + OFF_CSQ;
  float* s2  = ws + OFF_S2;  float* t2 = ws + OFF_T2;
  float* h2f = ws + OFF_H2F;
  float* qb  = ws + OFF_Q; float* kb = ws + OFF_K; float* vb = ws + OFF_V;
  float* out = (float*)d_out;
  float* h1  = out;   // d_out doubles as h1 scratch (consumed before attn writes)

  hipMemsetAsync(ws, 0, 2048 * sizeof(float), stream);           // zero stat accumulators
  k_xyz_stats<<<64, 256, 0, stream>>>(xyz, mom);
  k_bn1_coeff<<<1, 128, 0, stream>>>(mom, W1, g1, be1, s1, t1);
  k_pn1<<<(NROWS*HDIM)/256, 256, 0, stream>>>(xyz, W1, s1, t1, h1);
  k_gemm<<<dim3(NROWS/128, DDIM/128), 256, 0, stream>>>(h1, W2, b2, h2f, NROWS, DDIM, HDIM);
  k_colstats<<<256, 256, 0, stream>>>(h2f, cs, cq);
  k_bn2_coeff<<<1, 256, 0, stream>>>(cs, cq, g2, be2, s2, t2);
  k_makef<<<(NROWS*DDIM/4)/256, 256, 0, stream>>>(h2f, feats, s2, t2);
  k_gemm<<<dim3(NROWS/128, DDIM/128), 256, 0, stream>>>(h2f, Wq, nullptr, qb, NROWS, DDIM, DDIM);
  k_gemm<<<dim3(NROWS/128, DDIM/128), 256, 0, stream>>>(h2f, Wk, nullptr, kb, NROWS, DDIM, DDIM);
  k_gemm<<<dim3(NROWS/128, DDIM/128), 256, 0, stream>>>(h2f, Wv, nullptr, vb, NROWS, DDIM, DDIM);
  k_attn<<<512, 256, 0, stream>>>(qb, kb, vb, out);
}

// Round 4
// 498.906 us; speedup vs baseline: 5.4273x; 5.4273x over previous
//
#include <hip/hip_runtime.h>
#include <hip/hip_bf16.h>
#include <math.h>

#define NROWS 16384   // b*n
#define DDIM  256
#define HDIM  128
#define NSEQ  4096
#define NB    4

typedef unsigned short u16;
typedef __attribute__((ext_vector_type(8)))  short short8;
typedef __attribute__((ext_vector_type(16))) float f32x16;

// ---- workspace layout (float offsets) ----
#define OFF_MOM   0
#define OFF_S1    16
#define OFF_T1    144
#define OFF_CSUM  272
#define OFF_CSQ   528
#define OFF_S2    784
#define OFF_T2    1040
#define OFF_H2F   2048
#define OFF_Q     (OFF_H2F + NROWS*DDIM)            // bf16 (u16), uses NROWS*DDIM/2 float slots
#define OFF_K     (OFF_Q  + NROWS*DDIM/2)
#define OFF_VT    (OFF_K  + NROWS*DDIM/2)
// h1 lives in d_out (8 MB <= 16 MB), consumed before attention writes output.

// ---------------- xyz second moments (analytic BN1 stats) ----------------
__global__ void k_xyz_stats(const float* __restrict__ xyz, float* __restrict__ mom) {
  int i = blockIdx.x * blockDim.x + threadIdx.x;
  float x = xyz[3*i+0], y = xyz[3*i+1], z = xyz[3*i+2];
  float v[9] = {x, y, z, x*x, x*y, x*z, y*y, y*z, z*z};
#pragma unroll
  for (int j = 0; j < 9; ++j) {
    float s = v[j];
#pragma unroll
    for (int off = 32; off > 0; off >>= 1) s += __shfl_down(s, off);
    if ((threadIdx.x & 63) == 0) atomicAdd(&mom[j], s);
  }
}

__global__ void k_bn1_coeff(const float* __restrict__ mom, const float* __restrict__ W1,
                            const float* __restrict__ g1, const float* __restrict__ be1,
                            float* __restrict__ s1, float* __restrict__ t1) {
  int j = threadIdx.x;  // 128
  const float invN = 1.0f / NROWS;
  float mu0 = mom[0]*invN, mu1 = mom[1]*invN, mu2 = mom[2]*invN;
  float c00 = mom[3]*invN - mu0*mu0, c01 = mom[4]*invN - mu0*mu1, c02 = mom[5]*invN - mu0*mu2;
  float c11 = mom[6]*invN - mu1*mu1, c12 = mom[7]*invN - mu1*mu2, c22 = mom[8]*invN - mu2*mu2;
  float w0 = W1[j], w1 = W1[HDIM + j], w2 = W1[2*HDIM + j];
  float meanw = mu0*w0 + mu1*w1 + mu2*w2;
  float var = c00*w0*w0 + c11*w1*w1 + c22*w2*w2
            + 2.0f*(c01*w0*w1 + c02*w0*w2 + c12*w1*w2);
  float s = g1[j] * rsqrtf(var + 1e-5f);
  s1[j] = s;
  t1[j] = be1[j] - meanw * s;
}

__global__ void k_pn1(const float* __restrict__ xyz, const float* __restrict__ W1,
                      const float* __restrict__ s1, const float* __restrict__ t1,
                      float* __restrict__ h1) {
  int t = blockIdx.x * blockDim.x + threadIdx.x;
  int j = t & (HDIM-1), row = t >> 7;
  float x = xyz[3*row+0], y = xyz[3*row+1], z = xyz[3*row+2];
  float acc = x*W1[j] + y*W1[HDIM + j] + z*W1[2*HDIM + j];
  float v = fmaf(acc, s1[j], t1[j]);
  h1[t] = fmaxf(v, 0.0f);
}

// ---------------- fp32 GEMM, templated epilogue ----------------
// OM=0: f32 out. OM=1: bf16 row-major out. OM=2: bf16 transposed out per batch [256][4096].
template<int OM>
__global__ __launch_bounds__(256) void k_gemm(const float* __restrict__ A,
    const float* __restrict__ B, const float* __restrict__ bias,
    void* __restrict__ Cv, int M, int N, int K) {
  __shared__ float As[16][132];
  __shared__ float Bs[16][132];
  const int tid = threadIdx.x;
  const int tx = tid & 15, ty = tid >> 4;
  const int m0 = blockIdx.x * 128, n0 = blockIdx.y * 128;
  float acc[2][4][2][4] = {};

  for (int kb = 0; kb < K; kb += 16) {
    __syncthreads();
#pragma unroll
    for (int u = 0; u < 2; ++u) {
      int idx4 = tid + u * 256;
      int am = idx4 >> 2, ak = (idx4 & 3) << 2;
      float4 av = *(const float4*)&A[(size_t)(m0 + am) * K + kb + ak];
      As[ak+0][am] = av.x; As[ak+1][am] = av.y; As[ak+2][am] = av.z; As[ak+3][am] = av.w;
      int bk = idx4 >> 5, bc = (idx4 & 31) << 2;
      float4 bv = *(const float4*)&B[(size_t)(kb + bk) * N + n0 + bc];
      *(float4*)&Bs[bk][bc] = bv;
    }
    __syncthreads();
#pragma unroll
    for (int kk = 0; kk < 16; ++kk) {
      float4 a0 = *(const float4*)&As[kk][4*ty];
      float4 a1 = *(const float4*)&As[kk][64 + 4*ty];
      float4 b0 = *(const float4*)&Bs[kk][4*tx];
      float4 b1 = *(const float4*)&Bs[kk][64 + 4*tx];
      float av[2][4] = {{a0.x,a0.y,a0.z,a0.w},{a1.x,a1.y,a1.z,a1.w}};
      float bv[2][4] = {{b0.x,b0.y,b0.z,b0.w},{b1.x,b1.y,b1.z,b1.w}};
#pragma unroll
      for (int ri = 0; ri < 2; ++ri)
#pragma unroll
        for (int i = 0; i < 4; ++i)
#pragma unroll
          for (int rj = 0; rj < 2; ++rj)
#pragma unroll
            for (int j = 0; j < 4; ++j)
              acc[ri][i][rj][j] = fmaf(av[ri][i], bv[rj][j], acc[ri][i][rj][j]);
    }
  }

  if (OM == 0) {
    float* C = (float*)Cv;
#pragma unroll
    for (int ri = 0; ri < 2; ++ri)
#pragma unroll
      for (int i = 0; i < 4; ++i) {
        int r = m0 + ri*64 + 4*ty + i;
#pragma unroll
        for (int rj = 0; rj < 2; ++rj) {
          int c = n0 + rj*64 + 4*tx;
          float4 o;
          o.x = acc[ri][i][rj][0]; o.y = acc[ri][i][rj][1];
          o.z = acc[ri][i][rj][2]; o.w = acc[ri][i][rj][3];
          if (bias) { o.x += bias[c]; o.y += bias[c+1]; o.z += bias[c+2]; o.w += bias[c+3]; }
          *(float4*)&C[(size_t)r * N + c] = o;
        }
      }
  } else if (OM == 1) {
    u16* Cb = (u16*)Cv;
#pragma unroll
    for (int ri = 0; ri < 2; ++ri)
#pragma unroll
      for (int i = 0; i < 4; ++i) {
        int r = m0 + ri*64 + 4*ty + i;
#pragma unroll
        for (int rj = 0; rj < 2; ++rj) {
          int c = n0 + rj*64 + 4*tx;
          __hip_bfloat162 p0 = __float22bfloat162_rn(make_float2(acc[ri][i][rj][0], acc[ri][i][rj][1]));
          __hip_bfloat162 p1 = __float22bfloat162_rn(make_float2(acc[ri][i][rj][2], acc[ri][i][rj][3]));
          union { __hip_bfloat162 b[2]; uint2 u; } pk; pk.b[0] = p0; pk.b[1] = p1;
          *(uint2*)&Cb[(size_t)r * N + c] = pk.u;
        }
      }
  } else {
    // transposed: VT[(bi*256 + d) * 4096 + token], pack 4 consecutive tokens
    u16* Cb = (u16*)Cv;
    int bi = m0 >> 12, tok0 = m0 & (NSEQ-1);
#pragma unroll
    for (int ri = 0; ri < 2; ++ri)
#pragma unroll
      for (int rj = 0; rj < 2; ++rj)
#pragma unroll
        for (int j = 0; j < 4; ++j) {
          int dg = n0 + rj*64 + 4*tx + j;
          int tk = tok0 + ri*64 + 4*ty;
          __hip_bfloat162 p0 = __float22bfloat162_rn(make_float2(acc[ri][0][rj][j], acc[ri][1][rj][j]));
          __hip_bfloat162 p1 = __float22bfloat162_rn(make_float2(acc[ri][2][rj][j], acc[ri][3][rj][j]));
          union { __hip_bfloat162 b[2]; uint2 u; } pk; pk.b[0] = p0; pk.b[1] = p1;
          *(uint2*)&Cb[((size_t)(bi*DDIM + dg))*NSEQ + tk] = pk.u;
        }
  }
}

// per-column sum / sumsq of h2pre (for BN2)
__global__ void k_colstats(const float* __restrict__ h2, float* __restrict__ cs,
                           float* __restrict__ cq) {
  int j = threadIdx.x;
  size_t r0 = (size_t)blockIdx.x * 64;
  float s = 0.f, q = 0.f;
  for (int r = 0; r < 64; ++r) {
    float v = h2[(r0 + r) * DDIM + j];
    s += v; q += v * v;
  }
  atomicAdd(&cs[j], s);
  atomicAdd(&cq[j], q);
}

__global__ void k_bn2_coeff(const float* __restrict__ cs, const float* __restrict__ cq,
                            const float* __restrict__ g2, const float* __restrict__ be2,
                            float* __restrict__ s2, float* __restrict__ t2) {
  int j = threadIdx.x;
  const float invN = 1.0f / NROWS;
  float mean = cs[j] * invN;
  float var = cq[j] * invN - mean * mean;
  float s = g2[j] * rsqrtf(var + 1e-5f);
  s2[j] = s;
  t2[j] = be2[j] - mean * s;
}

__global__ void k_makef(float* __restrict__ h2f, const float* __restrict__ feats,
                        const float* __restrict__ s2, const float* __restrict__ t2) {
  size_t i4 = (size_t)blockIdx.x * blockDim.x + threadIdx.x;
  int c = ((int)i4 & 63) << 2;
  float4 h = *(float4*)&h2f[i4*4];
  float4 f = *(const float4*)&feats[i4*4];
  float4 s = *(const float4*)&s2[c];
  float4 t = *(const float4*)&t2[c];
  h.x = fmaxf(fmaf(h.x, s.x, t.x), 0.f) + f.x;
  h.y = fmaxf(fmaf(h.y, s.y, t.y), 0.f) + f.y;
  h.z = fmaxf(fmaf(h.z, s.z, t.z), 0.f) + f.z;
  h.w = fmaxf(fmaf(h.w, s.w, t.w), 0.f) + f.w;
  *(float4*)&h2f[i4*4] = h;
}

// ---------------- bf16 MFMA flash attention ----------------
// grid 256 = 4 batches x 64 q-tiles(64 rows); block 128 = 2 waves x 32 q-rows.
// Swapped QK^T: S^T = K*Q^T via mfma_f32_32x32x16_bf16 (D: col=q=lane&31,
// row=key=(reg&3)+8*(reg>>2)+4*(lane>>5)). Softmax per q-col: 1 shfl_xor(32).
// PV: O^T[d][q] = V^T * P^T, A=V^T from LDS (staged from pre-transposed global V^T),
// B=P^T rebuilt in-register via cvt+2 shfl_xor per word-pair.
// K LDS [64][256] bf16 XOR-swizzled; V^T LDS [256][64] bf16 XOR-swizzled.
// Staging: global_load_lds w=16, source pre-swizzled, double-buffered (128KB).
__device__ __forceinline__ void gload16(const void* g, void* l) {
  __builtin_amdgcn_global_load_lds((__attribute__((address_space(1))) void*)(g),
                                   (__attribute__((address_space(3))) void*)(l), 16, 0, 0);
}

__global__ __launch_bounds__(128, 1) void k_attn(const u16* __restrict__ Qg,
    const u16* __restrict__ Kg, const u16* __restrict__ VTg, float* __restrict__ Og) {
  __shared__ uint4 lds4[131072/16];          // 128KB: 2 bufs x (K 32KB | VT 32KB)
  char* lds = (char*)lds4;
  const int tid = threadIdx.x;
  const int w = tid >> 6, l = tid & 63;
  const int c = l & 31, h = l >> 5;
  const int bi = blockIdx.x >> 6, qt = blockIdx.x & 63;
  const int qrow = qt*64 + w*32 + c;                       // within batch
  const size_t qgbase = ((size_t)bi*NSEQ + qrow)*DDIM;

  // Q fragments in registers: 16 x short8 (B-operand: col=q=lane&31, k=(lane>>5)*8+i)
  short8 qf[16];
#pragma unroll
  for (int dblk = 0; dblk < 16; ++dblk)
    qf[dblk] = *(const short8*)(Qg + qgbase + dblk*16 + h*8);

  f32x16 oacc[8];
#pragma unroll
  for (int dt = 0; dt < 8; ++dt)
#pragma unroll
    for (int r = 0; r < 16; ++r) oacc[dt][r] = 0.f;
  float m = -1e30f, lsum = 0.f;

  // staging: wave w -> K rows [w*32, w*32+32), VT rows [w*128, w*128+128)
  auto stage = [&](int t, int bf) {
    char* base = lds + bf*65536;
    const int rk0 = w*32;
#pragma unroll
    for (int ii = 0; ii < 16; ++ii) {
      int row = rk0 + ii*2 + (l>>5);                       // 2 rows / instr
      int gslot = (l & 31) ^ (row & 7);
      const u16* gp = Kg + ((size_t)bi*NSEQ + (size_t)t*64 + row)*DDIM + gslot*8;
      gload16(gp, base + (rk0 + ii*2)*512);
    }
    const int rv0 = w*128;
#pragma unroll
    for (int ii = 0; ii < 16; ++ii) {
      int row = rv0 + ii*8 + (l>>3);                       // 8 rows / instr
      int gslot = (l & 7) ^ (row & 7);
      const u16* gp = VTg + ((size_t)(bi*DDIM + row))*NSEQ + (size_t)t*64 + gslot*8;
      gload16(gp, base + 32768 + (rv0 + ii*8)*128);
    }
  };

  stage(0, 0);
  __syncthreads();

  const int NT = NSEQ/64;
  for (int t = 0; t < NT; ++t) {
    const int cur = t & 1;
    if (t+1 < NT) stage(t+1, cur^1);                       // async DMA overlaps compute
    const char* kbuf = lds + cur*65536;
    const char* vbuf = kbuf + 32768;

    // S^T = K*Q^T  (two 32-key sub-tiles, interleaved acc chains)
    f32x16 st[2];
#pragma unroll
    for (int r = 0; r < 16; ++r) { st[0][r] = 0.f; st[1][r] = 0.f; }
#pragma unroll
    for (int dblk = 0; dblk < 16; ++dblk) {
#pragma unroll
      for (int kt = 0; kt < 2; ++kt) {
        int row = kt*32 + c;
        int byte = row*512 + ((dblk*32 + h*16) ^ ((row&7)<<4));
        short8 af = *(const short8*)(kbuf + byte);
        st[kt] = __builtin_amdgcn_mfma_f32_32x32x16_bf16(af, qf[dblk], st[kt], 0, 0, 0);
      }
    }

#pragma unroll
    for (int kt = 0; kt < 2; ++kt) {
      float p[16];
#pragma unroll
      for (int r = 0; r < 16; ++r) p[r] = st[kt][r] * 0.0625f;   // fold 1/sqrt(256)
      float tm = p[0];
#pragma unroll
      for (int r = 1; r < 16; ++r) tm = fmaxf(tm, p[r]);
      tm = fmaxf(tm, __shfl_xor(tm, 32));
      if (!__all(tm <= m + 8.0f)) {                        // defer-max (T13)
        float mn = fmaxf(m, tm);
        float corr = __expf(m - mn);
        lsum *= corr;
#pragma unroll
        for (int dt = 0; dt < 8; ++dt)
#pragma unroll
          for (int r = 0; r < 16; ++r) oacc[dt][r] *= corr;
        m = mn;
      }
      float ps = 0.f;
#pragma unroll
      for (int r = 0; r < 16; ++r) { p[r] = __expf(p[r] - m); ps += p[r]; }
      ps += __shfl_xor(ps, 32);
      lsum += ps;

      // P^T redistribution -> B-frags; PV accumulate
#pragma unroll
      for (int sub = 0; sub < 2; ++sub) {
        union { __hip_bfloat162 b; unsigned int u; } cv;
        cv.b = __float22bfloat162_rn(make_float2(p[((2*sub+0)<<2)|0], p[((2*sub+0)<<2)|1]));
        unsigned int X = cv.u;
        cv.b = __float22bfloat162_rn(make_float2(p[((2*sub+0)<<2)|2], p[((2*sub+0)<<2)|3]));
        unsigned int X2 = cv.u;
        cv.b = __float22bfloat162_rn(make_float2(p[((2*sub+1)<<2)|0], p[((2*sub+1)<<2)|1]));
        unsigned int Y = cv.u;
        cv.b = __float22bfloat162_rn(make_float2(p[((2*sub+1)<<2)|2], p[((2*sub+1)<<2)|3]));
        unsigned int Y2 = cv.u;
        unsigned int sx  = __shfl_xor(X, 32),  sx2 = __shfl_xor(X2, 32);
        unsigned int sy  = __shfl_xor(Y, 32),  sy2 = __shfl_xor(Y2, 32);
        union { unsigned int u[4]; short8 s; } bfw;
        bfw.u[0] = h ? sy  : X;    // keys i=0,1
        bfw.u[1] = h ? sy2 : X2;   // keys i=2,3
        bfw.u[2] = h ? Y   : sx;   // keys i=4,5
        bfw.u[3] = h ? Y2  : sx2;  // keys i=6,7
        const int koff = kt*2 + sub;                       // 16-key block in tile
#pragma unroll
        for (int dt = 0; dt < 8; ++dt) {
          int row = dt*32 + c;
          int byte = row*128 + ((koff*32 + h*16) ^ ((row&7)<<4));
          short8 vf = *(const short8*)(vbuf + byte);
          oacc[dt] = __builtin_amdgcn_mfma_f32_32x32x16_bf16(vf, bfw.s, oacc[dt], 0, 0, 0);
        }
      }
    }
    __syncthreads();                                       // drains DMA for t+1, joins waves
  }

  const float inv = 1.0f / lsum;
  const size_t obase = ((size_t)bi*NSEQ + qrow)*DDIM;
#pragma unroll
  for (int dt = 0; dt < 8; ++dt)
#pragma unroll
    for (int g = 0; g < 4; ++g) {
      float4 o4 = make_float4(oacc[dt][4*g+0]*inv, oacc[dt][4*g+1]*inv,
                              oacc[dt][4*g+2]*inv, oacc[dt][4*g+3]*inv);
      *(float4*)&Og[obase + dt*32 + g*8 + h*4] = o4;
    }
}

extern "C" void kernel_launch(void* const* d_in, const int* in_sizes, int n_in,
                              void* d_out, int out_size, void* d_ws, size_t ws_size,
                              hipStream_t stream) {
  (void)in_sizes; (void)n_in; (void)out_size; (void)ws_size;
  const float* xyz   = (const float*)d_in[0];
  const float* feats = (const float*)d_in[1];
  const float* W1    = (const float*)d_in[2];
  const float* g1    = (const float*)d_in[4];
  const float* be1   = (const float*)d_in[5];
  const float* W2    = (const float*)d_in[6];
  const float* b2    = (const float*)d_in[7];
  const float* g2    = (const float*)d_in[8];
  const float* be2   = (const float*)d_in[9];
  const float* Wq    = (const float*)d_in[10];
  const float* Wk    = (const float*)d_in[11];
  const float* Wv    = (const float*)d_in[12];

  float* ws  = (float*)d_ws;
  float* mom = ws + OFF_MOM;
  float* s1  = ws + OFF_S1;   float* t1 = ws + OFF_T1;
  float* cs  = ws + OFF_CSUM; float* cq = ws + OFF_CSQ;
  float* s2  = ws + OFF_S2;   float* t2 = ws + OFF_T2;
  float* h2f = ws + OFF_H2F;
  u16* qb  = (u16*)(ws + OFF_Q);
  u16* kb  = (u16*)(ws + OFF_K);
  u16* vtb = (u16*)(ws + OFF_VT);
  float* out = (float*)d_out;
  float* h1  = out;   // d_out doubles as h1 scratch (consumed before attn writes)

  hipMemsetAsync(ws, 0, 2048 * sizeof(float), stream);
  k_xyz_stats<<<64, 256, 0, stream>>>(xyz, mom);
  k_bn1_coeff<<<1, 128, 0, stream>>>(mom, W1, g1, be1, s1, t1);
  k_pn1<<<(NROWS*HDIM)/256, 256, 0, stream>>>(xyz, W1, s1, t1, h1);
  k_gemm<0><<<dim3(NROWS/128, DDIM/128), 256, 0, stream>>>(h1, W2, b2, h2f, NROWS, DDIM, HDIM);
  k_colstats<<<256, 256, 0, stream>>>(h2f, cs, cq);
  k_bn2_coeff<<<1, 256, 0, stream>>>(cs, cq, g2, be2, s2, t2);
  k_makef<<<(NROWS*DDIM/4)/256, 256, 0, stream>>>(h2f, feats, s2, t2);
  k_gemm<1><<<dim3(NROWS/128, DDIM/128), 256, 0, stream>>>(h2f, Wq, nullptr, qb,  NROWS, DDIM, DDIM);
  k_gemm<1><<<dim3(NROWS/128, DDIM/128), 256, 0, stream>>>(h2f, Wk, nullptr, kb,  NROWS, DDIM, DDIM);
  k_gemm<2><<<dim3(NROWS/128, DDIM/128), 256, 0, stream>>>(h2f, Wv, nullptr, vtb, NROWS, DDIM, DDIM);
  k_attn<<<256, 128, 0, stream>>>(qb, kb, vtb, out);
}

// Round 9
// 447.694 us; speedup vs baseline: 6.0481x; 1.1144x over previous
//
#include <hip/hip_runtime.h>
#include <hip/hip_bf16.h>
#include <math.h>

#define NROWS 16384   // b*n
#define DDIM  256
#define HDIM  128
#define NSEQ  4096
#define NB    4

typedef unsigned short u16;
typedef __attribute__((ext_vector_type(8)))  short short8;
typedef __attribute__((ext_vector_type(16))) float f32x16;

// ---- workspace layout (float offsets) ----
#define OFF_MOM   0
#define OFF_S1    16
#define OFF_T1    144
#define OFF_CSUM  272
#define OFF_CSQ   528
#define OFF_S2    784
#define OFF_T2    1040
#define OFF_H2F   2048
#define OFF_Q     (OFF_H2F + NROWS*DDIM)            // bf16 (u16)
#define OFF_K     (OFF_Q  + NROWS*DDIM/2)
#define OFF_VT    (OFF_K  + NROWS*DDIM/2)
#define OFF_FB    (OFF_VT + NROWS*DDIM/2)           // bf16 f (proj input)
#define OFF_WT    (OFF_FB + NROWS*DDIM/2)           // bf16 WT[3][256][256]
// h1 lives in d_out (8 MB <= 16 MB), consumed before attention writes output.

// ---------------- xyz second moments (analytic BN1 stats) ----------------
__global__ void k_xyz_stats(const float* __restrict__ xyz, float* __restrict__ mom) {
  int i = blockIdx.x * blockDim.x + threadIdx.x;
  float x = xyz[3*i+0], y = xyz[3*i+1], z = xyz[3*i+2];
  float v[9] = {x, y, z, x*x, x*y, x*z, y*y, y*z, z*z};
#pragma unroll
  for (int j = 0; j < 9; ++j) {
    float s = v[j];
#pragma unroll
    for (int off = 32; off > 0; off >>= 1) s += __shfl_down(s, off);
    if ((threadIdx.x & 63) == 0) atomicAdd(&mom[j], s);
  }
}

__global__ void k_bn1_coeff(const float* __restrict__ mom, const float* __restrict__ W1,
                            const float* __restrict__ g1, const float* __restrict__ be1,
                            float* __restrict__ s1, float* __restrict__ t1) {
  int j = threadIdx.x;  // 128
  const float invN = 1.0f / NROWS;
  float mu0 = mom[0]*invN, mu1 = mom[1]*invN, mu2 = mom[2]*invN;
  float c00 = mom[3]*invN - mu0*mu0, c01 = mom[4]*invN - mu0*mu1, c02 = mom[5]*invN - mu0*mu2;
  float c11 = mom[6]*invN - mu1*mu1, c12 = mom[7]*invN - mu1*mu2, c22 = mom[8]*invN - mu2*mu2;
  float w0 = W1[j], w1 = W1[HDIM + j], w2 = W1[2*HDIM + j];
  float meanw = mu0*w0 + mu1*w1 + mu2*w2;
  float var = c00*w0*w0 + c11*w1*w1 + c22*w2*w2
            + 2.0f*(c01*w0*w1 + c02*w0*w2 + c12*w1*w2);
  float s = g1[j] * rsqrtf(var + 1e-5f);
  s1[j] = s;
  t1[j] = be1[j] - meanw * s;
}

__global__ void k_pn1(const float* __restrict__ xyz, const float* __restrict__ W1,
                      const float* __restrict__ s1, const float* __restrict__ t1,
                      float* __restrict__ h1) {
  int t = blockIdx.x * blockDim.x + threadIdx.x;
  int j = t & (HDIM-1), row = t >> 7;
  float x = xyz[3*row+0], y = xyz[3*row+1], z = xyz[3*row+2];
  float acc = x*W1[j] + y*W1[HDIM + j] + z*W1[2*HDIM + j];
  float v = fmaf(acc, s1[j], t1[j]);
  h1[t] = fmaxf(v, 0.0f);
}

// ---------------- fp32 GEMM (only OM=0 instantiated now) ----------------
template<int OM>
__global__ __launch_bounds__(256) void k_gemm(const float* __restrict__ A,
    const float* __restrict__ B, const float* __restrict__ bias,
    void* __restrict__ Cv, int M, int N, int K) {
  __shared__ float As[16][132];
  __shared__ float Bs[16][132];
  const int tid = threadIdx.x;
  const int tx = tid & 15, ty = tid >> 4;
  const int m0 = blockIdx.x * 128, n0 = blockIdx.y * 128;
  float acc[2][4][2][4] = {};

  for (int kb = 0; kb < K; kb += 16) {
    __syncthreads();
#pragma unroll
    for (int u = 0; u < 2; ++u) {
      int idx4 = tid + u * 256;
      int am = idx4 >> 2, ak = (idx4 & 3) << 2;
      float4 av = *(const float4*)&A[(size_t)(m0 + am) * K + kb + ak];
      As[ak+0][am] = av.x; As[ak+1][am] = av.y; As[ak+2][am] = av.z; As[ak+3][am] = av.w;
      int bk = idx4 >> 5, bc = (idx4 & 31) << 2;
      float4 bv = *(const float4*)&B[(size_t)(kb + bk) * N + n0 + bc];
      *(float4*)&Bs[bk][bc] = bv;
    }
    __syncthreads();
#pragma unroll
    for (int kk = 0; kk < 16; ++kk) {
      float4 a0 = *(const float4*)&As[kk][4*ty];
      float4 a1 = *(const float4*)&As[kk][64 + 4*ty];
      float4 b0 = *(const float4*)&Bs[kk][4*tx];
      float4 b1 = *(const float4*)&Bs[kk][64 + 4*tx];
      float av[2][4] = {{a0.x,a0.y,a0.z,a0.w},{a1.x,a1.y,a1.z,a1.w}};
      float bv[2][4] = {{b0.x,b0.y,b0.z,b0.w},{b1.x,b1.y,b1.z,b1.w}};
#pragma unroll
      for (int ri = 0; ri < 2; ++ri)
#pragma unroll
        for (int i = 0; i < 4; ++i)
#pragma unroll
          for (int rj = 0; rj < 2; ++rj)
#pragma unroll
            for (int j = 0; j < 4; ++j)
              acc[ri][i][rj][j] = fmaf(av[ri][i], bv[rj][j], acc[ri][i][rj][j]);
    }
  }

  if (OM == 0) {
    float* C = (float*)Cv;
#pragma unroll
    for (int ri = 0; ri < 2; ++ri)
#pragma unroll
      for (int i = 0; i < 4; ++i) {
        int r = m0 + ri*64 + 4*ty + i;
#pragma unroll
        for (int rj = 0; rj < 2; ++rj) {
          int c = n0 + rj*64 + 4*tx;
          float4 o;
          o.x = acc[ri][i][rj][0]; o.y = acc[ri][i][rj][1];
          o.z = acc[ri][i][rj][2]; o.w = acc[ri][i][rj][3];
          if (bias) { o.x += bias[c]; o.y += bias[c+1]; o.z += bias[c+2]; o.w += bias[c+3]; }
          *(float4*)&C[(size_t)r * N + c] = o;
        }
      }
  }
}

// per-column sum / sumsq of h2pre (for BN2)
__global__ void k_colstats(const float* __restrict__ h2, float* __restrict__ cs,
                           float* __restrict__ cq) {
  int j = threadIdx.x;
  size_t r0 = (size_t)blockIdx.x * 64;
  float s = 0.f, q = 0.f;
  for (int r = 0; r < 64; ++r) {
    float v = h2[(r0 + r) * DDIM + j];
    s += v; q += v * v;
  }
  atomicAdd(&cs[j], s);
  atomicAdd(&cq[j], q);
}

__global__ void k_bn2_coeff(const float* __restrict__ cs, const float* __restrict__ cq,
                            const float* __restrict__ g2, const float* __restrict__ be2,
                            float* __restrict__ s2, float* __restrict__ t2) {
  int j = threadIdx.x;
  const float invN = 1.0f / NROWS;
  float mean = cs[j] * invN;
  float var = cq[j] * invN - mean * mean;
  float s = g2[j] * rsqrtf(var + 1e-5f);
  s2[j] = s;
  t2[j] = be2[j] - mean * s;
}

// f = relu(h2*s2 + t2) + features  -> bf16 fb (projection input)
__global__ void k_makef(const float* __restrict__ h2f, const float* __restrict__ feats,
                        const float* __restrict__ s2, const float* __restrict__ t2,
                        u16* __restrict__ fb) {
  size_t i4 = (size_t)blockIdx.x * blockDim.x + threadIdx.x;  // NROWS*DDIM/4
  int c = ((int)i4 & 63) << 2;
  float4 hh = *(const float4*)&h2f[i4*4];
  float4 ff = *(const float4*)&feats[i4*4];
  float4 s = *(const float4*)&s2[c];
  float4 t = *(const float4*)&t2[c];
  float a = fmaxf(fmaf(hh.x, s.x, t.x), 0.f) + ff.x;
  float b = fmaxf(fmaf(hh.y, s.y, t.y), 0.f) + ff.y;
  float d = fmaxf(fmaf(hh.z, s.z, t.z), 0.f) + ff.z;
  float e = fmaxf(fmaf(hh.w, s.w, t.w), 0.f) + ff.w;
  union { __hip_bfloat162 b2[2]; uint2 u; } pk;
  pk.b2[0] = __float22bfloat162_rn(make_float2(a, b));
  pk.b2[1] = __float22bfloat162_rn(make_float2(d, e));
  *(uint2*)&fb[i4*4] = pk.u;
}

// WT[o][n][k] = bf16(W_o[k][n])  (makes proj B-frag loads contiguous short8)
__global__ void k_wt(const float* __restrict__ Wq, const float* __restrict__ Wk,
                     const float* __restrict__ Wv, u16* __restrict__ WT) {
  const float* W = (blockIdx.y == 0) ? Wq : (blockIdx.y == 1) ? Wk : Wv;
  __shared__ float t[32][33];
  int n0 = (blockIdx.x & 7) * 32, k0 = (blockIdx.x >> 3) * 32;
  int tx = threadIdx.x & 31, ty = threadIdx.x >> 5;   // 32 x 8
#pragma unroll
  for (int i = 0; i < 4; ++i)
    t[ty + i*8][tx] = W[(size_t)(k0 + ty + i*8) * DDIM + n0 + tx];   // t[k][n]
  __syncthreads();
#pragma unroll
  for (int i = 0; i < 4; ++i) {
    int n = ty + i*8;
    union { __hip_bfloat16 b; u16 u; } cv;
    cv.b = __float2bfloat16(t[tx][n]);
    WT[((size_t)blockIdx.y * DDIM + n0 + n) * DDIM + k0 + tx] = cv.u;
  }
}

// ---------------- fused bf16 MFMA QKV projection ----------------
// grid (128, 3): blockIdx.y = output {q,k,vt}. 256 thr = 4 waves; wave w owns
// rows [bx*128+w*32, +32) x all 256 cols. No LDS: A/B short8 loads from global
// (WT 384KB L2-resident; patterns identical to validated k_attn fragments).
// mfma_f32_32x32x16_bf16: D col=lane&31(n), row=(r&3)+8*(r>>2)+4h (m-local).
__global__ __launch_bounds__(256, 2) void k_proj(const u16* __restrict__ fb,
    const u16* __restrict__ WT, u16* __restrict__ qb, u16* __restrict__ kb,
    u16* __restrict__ vtb) {
  const int tid = threadIdx.x;
  const int w = tid >> 6, l = tid & 63;
  const int c = l & 31, h = l >> 5;
  const int o = blockIdx.y;
  const int m0 = blockIdx.x * 128 + w * 32;
  const u16* WTo = WT + (size_t)o * DDIM * DDIM;

  f32x16 acc[8];
#pragma unroll
  for (int nt = 0; nt < 8; ++nt)
#pragma unroll
    for (int r = 0; r < 16; ++r) acc[nt][r] = 0.f;

  const u16* arow = fb  + (size_t)(m0 + c) * DDIM + h*8;
  const u16* brow = WTo + (size_t)c * DDIM + h*8;
  for (int s = 0; s < 16; ++s) {                       // K-steps of 16
    short8 af = *(const short8*)(arow + s*16);
#pragma unroll
    for (int nt = 0; nt < 8; ++nt) {
      short8 bf = *(const short8*)(brow + (size_t)nt*32*DDIM + s*16);
      acc[nt] = __builtin_amdgcn_mfma_f32_32x32x16_bf16(af, bf, acc[nt], 0, 0, 0);
    }
  }

  if (o < 2) {                                         // q/k: row-major bf16
    u16* C = o ? kb : qb;
#pragma unroll
    for (int nt = 0; nt < 8; ++nt)
#pragma unroll
      for (int r = 0; r < 16; ++r) {
        int row = m0 + (r & 3) + 8*(r >> 2) + 4*h;
        union { __hip_bfloat16 b; u16 u; } cv;
        cv.b = __float2bfloat16(acc[nt][r]);
        C[(size_t)row * DDIM + nt*32 + c] = cv.u;      // 64B/wave-row segments
      }
  } else {                                             // v: VT[bi*256+n][tok]
    const int bi = m0 >> 12, tloc = m0 & (NSEQ - 1);
#pragma unroll
    for (int nt = 0; nt < 8; ++nt)
#pragma unroll
      for (int g = 0; g < 4; ++g) {
        int t0 = tloc + 8*g + 4*h;                     // 4 consecutive tokens
        union { __hip_bfloat162 b2[2]; uint2 u; } pk;
        pk.b2[0] = __float22bfloat162_rn(make_float2(acc[nt][4*g+0], acc[nt][4*g+1]));
        pk.b2[1] = __float22bfloat162_rn(make_float2(acc[nt][4*g+2], acc[nt][4*g+3]));
        *(uint2*)&vtb[((size_t)(bi*DDIM + nt*32 + c)) * NSEQ + t0] = pk.u;
      }
  }
}

// ---------------- bf16 MFMA flash attention, split-K, no staging ----------------
// (unchanged from rounds 5-7; audited 4x, never yet executed)
__global__ __launch_bounds__(256, 2) void k_attn(const u16* __restrict__ Qg,
    const u16* __restrict__ Kg, const u16* __restrict__ VTg, float* __restrict__ Og) {
  __shared__ float sm4[4][32];
  __shared__ float sl4[4][32];
  __shared__ float sinv[32];
  __shared__ __align__(16) float sob[4][32][64];   // 32KB chunk buffer (swizzled float4s)

  const int tid = threadIdx.x;
  const int w = tid >> 6, l = tid & 63;
  const int c = l & 31, h = l >> 5;
  const int x = blockIdx.x & 7, grp = blockIdx.x >> 3;
  const int bi = x >> 1;                         // batch pinned to XCD pair
  const int qt = (x & 1) * 64 + grp;             // 0..127 q-tile (32 rows)
  const int qrow = qt * 32 + c;
  const size_t qgbase = ((size_t)bi * NSEQ + qrow) * DDIM;

  short8 qf[16];
#pragma unroll
  for (int dblk = 0; dblk < 16; ++dblk)
    qf[dblk] = *(const short8*)(Qg + qgbase + dblk*16 + h*8);

  f32x16 oacc[8];
#pragma unroll
  for (int dt = 0; dt < 8; ++dt)
#pragma unroll
    for (int r = 0; r < 16; ++r) oacc[dt][r] = 0.f;
  float m = -1e30f, lsum = 0.f;

  const u16* __restrict__ Kb  = Kg  + (size_t)bi * NSEQ * DDIM;
  const u16* __restrict__ VTb = VTg + (size_t)bi * DDIM * NSEQ;

  for (int t = 0; t < 32; ++t) {
    const int kb = w * 1024 + t * 32;

    f32x16 st;
#pragma unroll
    for (int r = 0; r < 16; ++r) st[r] = 0.f;
    const u16* Krow = Kb + (size_t)(kb + c) * DDIM + h*8;
#pragma unroll
    for (int dblk = 0; dblk < 16; ++dblk) {
      short8 af = *(const short8*)(Krow + dblk*16);
      st = __builtin_amdgcn_mfma_f32_32x32x16_bf16(af, qf[dblk], st, 0, 0, 0);
    }

    float p[16];
#pragma unroll
    for (int r = 0; r < 16; ++r) p[r] = st[r] * 0.0625f;     // fold 1/sqrt(256)
    float tm = p[0];
#pragma unroll
    for (int r = 1; r < 16; ++r) tm = fmaxf(tm, p[r]);
    tm = fmaxf(tm, __shfl_xor(tm, 32));
    if (!__all(tm <= m + 8.0f)) {                            // defer-max (T13)
      float mn = fmaxf(m, tm);
      float corr = __expf(m - mn);
      lsum *= corr;
#pragma unroll
      for (int dt = 0; dt < 8; ++dt)
#pragma unroll
        for (int r = 0; r < 16; ++r) oacc[dt][r] *= corr;
      m = mn;
    }
    float ps = 0.f;
#pragma unroll
    for (int r = 0; r < 16; ++r) { p[r] = __expf(p[r] - m); ps += p[r]; }
    ps += __shfl_xor(ps, 32);
    lsum += ps;

    short8 bfr[2];
#pragma unroll
    for (int sub = 0; sub < 2; ++sub) {
      union { __hip_bfloat162 b; unsigned int u; } cv;
      cv.b = __float22bfloat162_rn(make_float2(p[((2*sub+0)<<2)|0], p[((2*sub+0)<<2)|1]));
      unsigned int X = cv.u;
      cv.b = __float22bfloat162_rn(make_float2(p[((2*sub+0)<<2)|2], p[((2*sub+0)<<2)|3]));
      unsigned int X2 = cv.u;
      cv.b = __float22bfloat162_rn(make_float2(p[((2*sub+1)<<2)|0], p[((2*sub+1)<<2)|1]));
      unsigned int Y = cv.u;
      cv.b = __float22bfloat162_rn(make_float2(p[((2*sub+1)<<2)|2], p[((2*sub+1)<<2)|3]));
      unsigned int Y2 = cv.u;
      unsigned int sx  = __shfl_xor(X, 32),  sx2 = __shfl_xor(X2, 32);
      unsigned int sy  = __shfl_xor(Y, 32),  sy2 = __shfl_xor(Y2, 32);
      union { unsigned int u[4]; short8 s; } bfw;
      bfw.u[0] = h ? sy  : X;
      bfw.u[1] = h ? sy2 : X2;
      bfw.u[2] = h ? Y   : sx;
      bfw.u[3] = h ? Y2  : sx2;
      bfr[sub] = bfw.s;
    }
#pragma unroll
    for (int dt = 0; dt < 8; ++dt) {
      const u16* Vrow = VTb + (size_t)(dt*32 + c) * NSEQ + kb + h*8;
      short8 vf0 = *(const short8*)(Vrow);
      short8 vf1 = *(const short8*)(Vrow + 16);
      oacc[dt] = __builtin_amdgcn_mfma_f32_32x32x16_bf16(vf0, bfr[0], oacc[dt], 0, 0, 0);
      oacc[dt] = __builtin_amdgcn_mfma_f32_32x32x16_bf16(vf1, bfr[1], oacc[dt], 0, 0, 0);
    }
  }

  // ---- in-block split merge ----
  if (h == 0) { sm4[w][c] = m; sl4[w][c] = lsum; }
  __syncthreads();
  float M = fmaxf(fmaxf(sm4[0][c], sm4[1][c]), fmaxf(sm4[2][c], sm4[3][c]));
  float Ltot = 0.f, scl_w = 0.f;
#pragma unroll
  for (int i = 0; i < 4; ++i) {
    float e = __expf(sm4[i][c] - M);
    Ltot += sl4[i][c] * e;
    if (i == w) scl_w = e;
  }
  if (w == 0 && h == 0) sinv[c] = 1.0f / Ltot;
  __syncthreads();

  const int q = tid >> 3, ds0 = (tid & 7) * 8;
  const size_t orow = ((size_t)bi * NSEQ + qt*32 + q) * DDIM;
#pragma unroll
  for (int cc = 0; cc < 4; ++cc) {
#pragma unroll
    for (int dd = 0; dd < 2; ++dd) {
      const int dt = cc*2 + dd;
#pragma unroll
      for (int g = 0; g < 4; ++g) {
        int dloc = dd*32 + g*8 + h*4;
        float4 v4 = make_float4(oacc[dt][4*g+0]*scl_w, oacc[dt][4*g+1]*scl_w,
                                oacc[dt][4*g+2]*scl_w, oacc[dt][4*g+3]*scl_w);
        char* pdst = (char*)&sob[w][c][0] + ((dloc*4) ^ ((c&7)<<4));
        *(float4*)pdst = v4;
      }
    }
    __syncthreads();
    float r0=0,r1=0,r2=0,r3=0,r4=0,r5=0,r6=0,r7=0;
#pragma unroll
    for (int ww = 0; ww < 4; ++ww) {
      const char* base = (const char*)&sob[ww][q][0];
      float4 a = *(const float4*)(base + ((ds0*4)     ^ ((q&7)<<4)));
      float4 b = *(const float4*)(base + (((ds0+4)*4) ^ ((q&7)<<4)));
      r0+=a.x; r1+=a.y; r2+=a.z; r3+=a.w;
      r4+=b.x; r5+=b.y; r6+=b.z; r7+=b.w;
    }
    const float iv = sinv[q];
    float4 o0 = make_float4(r0*iv, r1*iv, r2*iv, r3*iv);
    float4 o1 = make_float4(r4*iv, r5*iv, r6*iv, r7*iv);
    *(float4*)&Og[orow + cc*64 + ds0]     = o0;
    *(float4*)&Og[orow + cc*64 + ds0 + 4] = o1;
    __syncthreads();
  }
}

extern "C" void kernel_launch(void* const* d_in, const int* in_sizes, int n_in,
                              void* d_out, int out_size, void* d_ws, size_t ws_size,
                              hipStream_t stream) {
  (void)in_sizes; (void)n_in; (void)out_size; (void)ws_size;
  const float* xyz   = (const float*)d_in[0];
  const float* feats = (const float*)d_in[1];
  const float* W1    = (const float*)d_in[2];
  const float* g1    = (const float*)d_in[4];
  const float* be1   = (const float*)d_in[5];
  const float* W2    = (const float*)d_in[6];
  const float* b2    = (const float*)d_in[7];
  const float* g2    = (const float*)d_in[8];
  const float* be2   = (const float*)d_in[9];
  const float* Wq    = (const float*)d_in[10];
  const float* Wk    = (const float*)d_in[11];
  const float* Wv    = (const float*)d_in[12];

  float* ws  = (float*)d_ws;
  float* mom = ws + OFF_MOM;
  float* s1  = ws + OFF_S1;   float* t1 = ws + OFF_T1;
  float* cs  = ws + OFF_CSUM; float* cq = ws + OFF_CSQ;
  float* s2  = ws + OFF_S2;   float* t2 = ws + OFF_T2;
  float* h2f = ws + OFF_H2F;
  u16* qb  = (u16*)(ws + OFF_Q);
  u16* kb  = (u16*)(ws + OFF_K);
  u16* vtb = (u16*)(ws + OFF_VT);
  u16* fb  = (u16*)(ws + OFF_FB);
  u16* wt  = (u16*)(ws + OFF_WT);
  float* out = (float*)d_out;
  float* h1  = out;   // d_out doubles as h1 scratch (consumed before attn writes)

  hipMemsetAsync(ws, 0, 2048 * sizeof(float), stream);
  k_xyz_stats<<<64, 256, 0, stream>>>(xyz, mom);
  k_bn1_coeff<<<1, 128, 0, stream>>>(mom, W1, g1, be1, s1, t1);
  k_pn1<<<(NROWS*HDIM)/256, 256, 0, stream>>>(xyz, W1, s1, t1, h1);
  k_wt<<<dim3(64, 3), 256, 0, stream>>>(Wq, Wk, Wv, wt);
  k_gemm<0><<<dim3(NROWS/128, DDIM/128), 256, 0, stream>>>(h1, W2, b2, h2f, NROWS, DDIM, HDIM);
  k_colstats<<<256, 256, 0, stream>>>(h2f, cs, cq);
  k_bn2_coeff<<<1, 256, 0, stream>>>(cs, cq, g2, be2, s2, t2);
  k_makef<<<(NROWS*DDIM/4)/256, 256, 0, stream>>>(h2f, feats, s2, t2, fb);
  k_proj<<<dim3(NROWS/128, 3), 256, 0, stream>>>(fb, wt, qb, kb, vtb);
  k_attn<<<512, 256, 0, stream>>>(qb, kb, vtb, out);
}